// Round 4
// baseline (263.495 us; speedup 1.0000x reference)
//
#include <hip/hip_runtime.h>
#include <hip/hip_bf16.h>
#include <stdint.h>

#define K_DIM 4096
#define N_DIM 11008
#define M_DIM 512
#define PK_ROW 5504          // int32 code-words per k-row (one per n-pair)
#define SC_ROW 172           // scale blocks per k-row
#define BM 64
#define BN 64
#define BK 64
#define NT (K_DIM / BK)      // 64 k-tiles

typedef __attribute__((ext_vector_type(8))) short bf16x8;
typedef __attribute__((ext_vector_type(4))) float f32x4;
typedef __attribute__((ext_vector_type(4))) int i32x4;
typedef __attribute__((ext_vector_type(4))) unsigned int u32x4;

__constant__ float NF4[16] = {
    -1.0f, -0.6961928009986877f, -0.5250730514526367f, -0.39491748809814453f,
    -0.28444138169288635f, -0.18477343022823334f, -0.09105003625154495f, 0.0f,
    0.07958029955625534f, 0.16093020141124725f, 0.24611230194568634f,
    0.33791524171829224f, 0.44070982933044434f, 0.5626170039176941f,
    0.7229568362236023f, 1.0f};

__device__ __forceinline__ unsigned f2bf(float v) {
  union { __hip_bfloat16 h; unsigned short u; } cv;
  cv.h = __float2bfloat16(v);
  return (unsigned)cv.u;
}

// ---- kernel 1: x fp32 -> bf16, MFMA-fragment-block layout in ws ----
// ws layout: block (m16, k32) = 1KB, addr = ((m16*128 + k32)*64 + lane)*16B
// lane l holds A[m16*16 + (l&15)][k32*32 + (l>>4)*8 .. +8)
__global__ __launch_bounds__(256) void conv_a(const float* __restrict__ x,
                                              unsigned short* __restrict__ wsa) {
  const int wid = blockIdx.x * 4 + (threadIdx.x >> 6);  // 4096 wave-tasks
  const int lane = threadIdx.x & 63;
  const int m16 = wid >> 7;   // 0..31
  const int k32 = wid & 127;  // 0..127
  const int m = m16 * 16 + (lane & 15);
  const int k = k32 * 32 + (lane >> 4) * 8;
  const float* src = x + (size_t)m * K_DIM + k;
  f32x4 v0 = *(const f32x4*)src;
  f32x4 v1 = *(const f32x4*)(src + 4);
  u32x4 d;
  d[0] = f2bf(v0[0]) | (f2bf(v0[1]) << 16);
  d[1] = f2bf(v0[2]) | (f2bf(v0[3]) << 16);
  d[2] = f2bf(v1[0]) | (f2bf(v1[1]) << 16);
  d[3] = f2bf(v1[2]) | (f2bf(v1[3]) << 16);
  *(u32x4*)(wsa + ((size_t)wid * 64 + lane) * 8) = d;
}

// ---- kernel 2: fused NF4-dequant GEMM ----
// 64x64 tile, 4 waves (2x2), wave tile 32x32, B double-buffered in LDS.
// Grid 1376 = 5.4 blocks/CU; launch_bounds(256,4) caps VGPR<=128 so >=4
// blocks/CU are resident (R3 lesson: grid 688 -> 17% occupancy was THE limit).
__global__ __launch_bounds__(256, 4) void nf4_gemm(
    const int* __restrict__ packed, const float* __restrict__ scales,
    const float* __restrict__ bias, const unsigned short* __restrict__ wsa,
    float* __restrict__ out) {
  // B buffers: [n][swizzled 128B of 64 k bf16], byte ^= ((n&7)<<4)
  __shared__ __align__(16) char Bbuf0[BN * 128];
  __shared__ __align__(16) char Bbuf1[BN * 128];
  __shared__ float2 Lut[256];

  const int t = threadIdx.x;
  // XCD swizzle: 1376 = 8*172 bijective; each XCD owns one 64-row m-slice
  // (A slice 512KB -> L2-resident)
  const int bid = blockIdx.x;
  const int swz = (bid & 7) * 172 + (bid >> 3);
  const int m_tile = (swz / 172) * BM;
  const int n_tile = (swz % 172) * BN;

  Lut[t] = make_float2(NF4[(t >> 4) & 15], NF4[t & 15]);

  const int lane = t & 63;
  const int wid = t >> 6;
  const int wm = (wid >> 1) * 32;
  const int wn = (wid & 1) * 32;
  const int l15 = lane & 15;
  const int l4 = lane >> 4;
  const int m16w = (m_tile >> 4) + (wid >> 1) * 2;  // wave's first m16 block

  // B staging: thread owns k-pair (2*kp, 2*kp+1) x n-octet noct*8..+7
  const int kp = t & 31;
  const int noct = t >> 5;
  const size_t pk_base = (size_t)(n_tile >> 1) + noct * 4;
  const int sc_col = n_tile >> 6;

  f32x4 acc[2][2];
#pragma unroll
  for (int i = 0; i < 2; ++i) {
    acc[i][0] = (f32x4){0.f, 0.f, 0.f, 0.f};
    acc[i][1] = (f32x4){0.f, 0.f, 0.f, 0.f};
  }

  i32x4 ga0, gb0, ga1, gb1;  // raw codes: (set0, set1) x (row k, row k+1)
  float s0a, s0b, s1a, s1b;
  bf16x8 a0[4], a1[4];

  auto loadB0 = [&](int tau) {
    const size_t kb = (size_t)tau * BK + 2 * kp;
    ga0 = *(const i32x4*)(packed + kb * PK_ROW + pk_base);
    gb0 = *(const i32x4*)(packed + (kb + 1) * PK_ROW + pk_base);
    s0a = scales[kb * SC_ROW + sc_col];
    s0b = scales[(kb + 1) * SC_ROW + sc_col];
  };
  auto loadB1 = [&](int tau) {
    const size_t kb = (size_t)tau * BK + 2 * kp;
    ga1 = *(const i32x4*)(packed + kb * PK_ROW + pk_base);
    gb1 = *(const i32x4*)(packed + (kb + 1) * PK_ROW + pk_base);
    s1a = scales[kb * SC_ROW + sc_col];
    s1b = scales[(kb + 1) * SC_ROW + sc_col];
  };
  auto dequant = [&](const i32x4& wa, const i32x4& wb, float sa, float sb,
                     char* buf) {
#pragma unroll
    for (int e = 0; e < 4; ++e) {
      const float2 p0 = Lut[wa[e] & 255];
      const float2 p1 = Lut[wb[e] & 255];
      const int n0 = noct * 8 + 2 * e;
      const unsigned v0 = f2bf(p0.x * sa) | (f2bf(p1.x * sb) << 16);
      *(unsigned*)(buf + n0 * 128 + ((4 * kp) ^ ((n0 & 7) << 4))) = v0;
      const int n1 = n0 + 1;
      const unsigned v1 = f2bf(p0.y * sa) | (f2bf(p1.y * sb) << 16);
      *(unsigned*)(buf + n1 * 128 + ((4 * kp) ^ ((n1 & 7) << 4))) = v1;
    }
  };
  auto loadA = [&](bf16x8* A, int tau) {
    const int k32 = tau * 2;
#pragma unroll
    for (int fm = 0; fm < 2; ++fm)
#pragma unroll
      for (int ks = 0; ks < 2; ++ks)
        A[fm * 2 + ks] = *(const bf16x8*)(wsa +
            (((size_t)(m16w + fm) * 128 + k32 + ks) * 64 + lane) * 8);
  };
  auto compute = [&](const char* buf, const bf16x8* A) {
    bf16x8 bfv[2][2];
#pragma unroll
    for (int fn = 0; fn < 2; ++fn) {
      const int n = wn + fn * 16 + l15;
#pragma unroll
      for (int ks = 0; ks < 2; ++ks)
        bfv[fn][ks] = *(const bf16x8*)(buf + n * 128 +
                                       ((ks * 64 + l4 * 16) ^ ((n & 7) << 4)));
    }
    __builtin_amdgcn_s_setprio(1);
#pragma unroll
    for (int fm = 0; fm < 2; ++fm)
#pragma unroll
      for (int fn = 0; fn < 2; ++fn) {
        acc[fm][fn] = __builtin_amdgcn_mfma_f32_16x16x32_bf16(
            A[fm * 2 + 0], bfv[fn][0], acc[fm][fn], 0, 0, 0);
        acc[fm][fn] = __builtin_amdgcn_mfma_f32_16x16x32_bf16(
            A[fm * 2 + 1], bfv[fn][1], acc[fm][fn], 0, 0, 0);
      }
    __builtin_amdgcn_s_setprio(0);
  };

  // prologue
  loadB0(0);
  loadB1(1);
  loadA(a0, 0);
  loadA(a1, 1);
  __syncthreads();  // Lut visible
  dequant(ga0, gb0, s0a, s0b, Bbuf0);
  loadB0(2);
  __syncthreads();  // Bbuf0 ready

#pragma unroll 1
  for (int tt = 0; tt < NT / 2; ++tt) {
    // even tile 2tt: compute Bbuf0/a0; stage tile 2tt+1 -> Bbuf1
    dequant(ga1, gb1, s1a, s1b, Bbuf1);
    if (tt < NT / 2 - 1) loadB1(2 * tt + 3);
    compute(Bbuf0, a0);
    if (tt < NT / 2 - 1) loadA(a0, 2 * tt + 2);
    __syncthreads();  // Bbuf1 ready, Bbuf0 free
    // odd tile 2tt+1: compute Bbuf1/a1; stage tile 2tt+2 -> Bbuf0
    if (tt < NT / 2 - 1) {
      dequant(ga0, gb0, s0a, s0b, Bbuf0);
      // guard: tile 2tt+4 only exists for tt < NT/2-2 (R2 OOB lesson)
      if (tt < NT / 2 - 2) loadB0(2 * tt + 4);
    }
    compute(Bbuf1, a1);
    if (tt < NT / 2 - 1) loadA(a1, 2 * tt + 3);
    __syncthreads();  // Bbuf0 ready, Bbuf1 free
  }

  // epilogue
#pragma unroll
  for (int fn = 0; fn < 2; ++fn) {
    const int gc = n_tile + wn + fn * 16 + l15;
    const float bi = bias[gc];
#pragma unroll
    for (int fm = 0; fm < 2; ++fm) {
#pragma unroll
      for (int r = 0; r < 4; ++r) {
        const int gr = m_tile + wm + fm * 16 + l4 * 4 + r;
        out[(size_t)gr * N_DIM + gc] = acc[fm][fn][r] + bi;
      }
    }
  }
}

// ---- fallback (round-1 kernel, passes at 155us): used only if ws too small ----
#define FLDS 72
__global__ __launch_bounds__(256) void nf4_gemm_fused(
    const float* __restrict__ x, const int* __restrict__ packed,
    const float* __restrict__ scales, const float* __restrict__ bias,
    float* __restrict__ out) {
  __shared__ unsigned short Alds[128 * FLDS];
  __shared__ unsigned short Blds[128 * FLDS];
  __shared__ float2 Lut[256];
  const int t = threadIdx.x;
  const int bid = blockIdx.x;
  const int swz = (bid & 7) * 43 + (bid >> 3);
  const int m_tile = (swz / 86) * 128;
  const int n_tile = (swz % 86) * 128;
  Lut[t] = make_float2(NF4[(t >> 4) & 15], NF4[t & 15]);
  const int lane = t & 63;
  const int wid = t >> 6;
  const int wm = (wid >> 1) * 64;
  const int wn = (wid & 1) * 64;
  const int l15 = lane & 15;
  const int l4 = lane >> 4;
  f32x4 acc[4][4];
#pragma unroll
  for (int i = 0; i < 4; ++i)
#pragma unroll
    for (int j = 0; j < 4; ++j) acc[i][j] = (f32x4){0.f, 0.f, 0.f, 0.f};
  const int mlane = t & 15;
  const int n_sub = mlane * 8;
  const int k_sub = 4 * (((t >> 4) + mlane) & 15);
  const int c4 = t & 15;
  const int r0 = t >> 4;
  for (int k0 = 0; k0 < K_DIM; k0 += 64) {
    __syncthreads();
#pragma unroll
    for (int i = 0; i < 8; ++i) {
      const int row = r0 + 16 * i;
      f32x4 xv = *(const f32x4*)(x + (size_t)(m_tile + row) * K_DIM + k0 + c4 * 4);
      uint2 d;
      d.x = f2bf(xv[0]) | (f2bf(xv[1]) << 16);
      d.y = f2bf(xv[2]) | (f2bf(xv[3]) << 16);
      *(uint2*)(&Alds[row * FLDS + c4 * 4]) = d;
    }
    {
      const int* pk = packed + (size_t)(k0 + k_sub) * PK_ROW + ((n_tile + n_sub) >> 1);
      i32x4 w[4];
      float s[4];
#pragma unroll
      for (int kk = 0; kk < 4; ++kk) {
        w[kk] = *(const i32x4*)(pk + (size_t)kk * PK_ROW);
        s[kk] = scales[(size_t)(k0 + k_sub + kk) * SC_ROW + ((n_tile + n_sub) >> 6)];
      }
      float v[4][8];
#pragma unroll
      for (int kk = 0; kk < 4; ++kk)
#pragma unroll
        for (int e = 0; e < 4; ++e) {
          const int b = w[kk][e] & 0xFF;
          const float2 p = Lut[b];
          v[kk][2 * e] = p.x * s[kk];
          v[kk][2 * e + 1] = p.y * s[kk];
        }
#pragma unroll
      for (int j = 0; j < 8; ++j) {
        uint2 d;
        d.x = f2bf(v[0][j]) | (f2bf(v[1][j]) << 16);
        d.y = f2bf(v[2][j]) | (f2bf(v[3][j]) << 16);
        *(uint2*)(&Blds[(n_sub + j) * FLDS + k_sub]) = d;
      }
    }
    __syncthreads();
#pragma unroll
    for (int ks = 0; ks < 2; ++ks) {
      bf16x8 af[4], bfv[4];
#pragma unroll
      for (int fm = 0; fm < 4; ++fm)
        af[fm] = *(const bf16x8*)(&Alds[(wm + fm * 16 + l15) * FLDS + ks * 32 + l4 * 8]);
#pragma unroll
      for (int fn = 0; fn < 4; ++fn)
        bfv[fn] = *(const bf16x8*)(&Blds[(wn + fn * 16 + l15) * FLDS + ks * 32 + l4 * 8]);
#pragma unroll
      for (int fm = 0; fm < 4; ++fm)
#pragma unroll
        for (int fn = 0; fn < 4; ++fn)
          acc[fm][fn] = __builtin_amdgcn_mfma_f32_16x16x32_bf16(af[fm], bfv[fn], acc[fm][fn], 0, 0, 0);
    }
  }
#pragma unroll
  for (int fn = 0; fn < 4; ++fn) {
    const float bi = bias[n_tile + wn + fn * 16 + l15];
#pragma unroll
    for (int fm = 0; fm < 4; ++fm)
#pragma unroll
      for (int r = 0; r < 4; ++r) {
        const int gr = m_tile + wm + fm * 16 + l4 * 4 + r;
        out[(size_t)gr * N_DIM + n_tile + wn + fn * 16 + l15] = acc[fm][fn][r] + bi;
      }
  }
}

extern "C" void kernel_launch(void* const* d_in, const int* in_sizes, int n_in,
                              void* d_out, int out_size, void* d_ws, size_t ws_size,
                              hipStream_t stream) {
  const float* x = (const float*)d_in[0];
  const int* packed = (const int*)d_in[1];
  const float* scales = (const float*)d_in[2];
  const float* bias = (const float*)d_in[3];
  float* out = (float*)d_out;

  const size_t need = (size_t)M_DIM * K_DIM * 2;  // 4MB bf16 A copy
  if (ws_size >= need) {
    unsigned short* wsa = (unsigned short*)d_ws;
    conv_a<<<dim3(1024), dim3(256), 0, stream>>>(x, wsa);
    nf4_gemm<<<dim3(1376), dim3(256), 0, stream>>>(packed, scales, bias, wsa, out);
  } else {
    nf4_gemm_fused<<<dim3(344), dim3(256), 0, stream>>>(x, packed, scales, bias, out);
  }
}

// Round 5
// 106.180 us; speedup vs baseline: 2.4816x; 2.4816x over previous
//
#include <hip/hip_runtime.h>
#include <hip/hip_bf16.h>
#include <hip/hip_fp16.h>
#include <stdint.h>

#define K_DIM 4096
#define N_DIM 11008
#define M_DIM 512
#define PK_ROW 5504          // int32 code-words per k-row (one per n-pair)
#define SC_ROW 172           // scale blocks per k-row

typedef __attribute__((ext_vector_type(4))) float f32x4;
typedef __attribute__((ext_vector_type(4))) int i32x4;
typedef __attribute__((ext_vector_type(4))) unsigned int u32x4;
typedef __attribute__((ext_vector_type(8))) _Float16 half8;
typedef __attribute__((ext_vector_type(8))) short bf16x8;

__constant__ float NF4[16] = {
    -1.0f, -0.6961928009986877f, -0.5250730514526367f, -0.39491748809814453f,
    -0.28444138169288635f, -0.18477343022823334f, -0.09105003625154495f, 0.0f,
    0.07958029955625534f, 0.16093020141124725f, 0.24611230194568634f,
    0.33791524171829224f, 0.44070982933044434f, 0.5626170039176941f,
    0.7229568362236023f, 1.0f};

union H8 { u32x4 v; half8 h; };

__device__ __forceinline__ unsigned h2mul(unsigned a, unsigned b) {
  union { __half2 h; unsigned u; } x, y, r;
  x.u = a; y.u = b;
  r.h = x.h * y.h;           // v_pk_mul_f16
  return r.u;
}
__device__ __forceinline__ unsigned hpack(float a, float b) {
  union { __half2 h; unsigned u; } c;
  c.h = __floats2half2_rn(a, b);
  return c.u;
}
__device__ __forceinline__ unsigned f2bf(float v) {  // for fallback kernel
  union { __hip_bfloat16 h; unsigned short u; } cv;
  cv.h = __float2bfloat16(v);
  return (unsigned)cv.u;
}

// ---- pre-pass 1: x fp32 -> f16, MFMA-fragment-block layout ----
// block (m16,k32) = 1KB; u32 idx = (m16*128+k32)*256 + lane*4
// lane l: A[m16*16+(l&15)][k32*32+(l>>4)*8 .. +8)
__global__ __launch_bounds__(256) void conv_a16(const float* __restrict__ x,
                                                unsigned* __restrict__ wsa) {
  const int wid = blockIdx.x * 4 + (threadIdx.x >> 6);
  const int lane = threadIdx.x & 63;
  const int m16 = wid >> 7, k32 = wid & 127;
  const int m = m16 * 16 + (lane & 15);
  const int k = k32 * 32 + (lane >> 4) * 8;
  const float* src = x + (size_t)m * K_DIM + k;
  f32x4 v0 = *(const f32x4*)src;
  f32x4 v1 = *(const f32x4*)(src + 4);
  u32x4 d;
  d[0] = hpack(v0[0], v0[1]);
  d[1] = hpack(v0[2], v0[3]);
  d[2] = hpack(v1[0], v1[1]);
  d[3] = hpack(v1[2], v1[3]);
  *(u32x4*)(wsa + (size_t)wid * 256 + lane * 4) = d;
}

// ---- pre-pass 2: transpose-compact codes ----
// in:  int32 word (k, npair) -> byte, hi nibble = even n, lo = odd n
// out: uint8 byte (n, kp) = code(2kp,n)<<4 | code(2kp+1,n), stored as dwords:
//      dword D = (n>>4)*8192/16... D = ((n>>4)*512 + (kp>>2))*16 + (n&15)
__global__ __launch_bounds__(256) void prep_codes(const int* __restrict__ packed,
                                                  unsigned* __restrict__ codes) {
  const int b = blockIdx.x;
  const int kt = b & 63;   // k-tile of 64
  const int nt = b >> 6;   // n-tile of 128 (0..85)
  __shared__ unsigned char Sb[128 * 36];  // [n_local][kp_local], pad 36 vs bank clash
  const int t = threadIdx.x;
  const int npl = t & 63;
  const int kq = t >> 6;
  const int np = nt * 64 + npl;
#pragma unroll
  for (int i = 0; i < 8; ++i) {
    const int kpl = kq + i * 4;               // 0..31
    const int k = kt * 64 + kpl * 2;
    const int w0 = packed[(size_t)k * PK_ROW + np];
    const int w1 = packed[(size_t)(k + 1) * PK_ROW + np];
    Sb[(npl * 2) * 36 + kpl] =
        (unsigned char)((((w0 >> 4) & 15) << 4) | ((w1 >> 4) & 15));  // even n
    Sb[(npl * 2 + 1) * 36 + kpl] =
        (unsigned char)(((w0 & 15) << 4) | (w1 & 15));                // odd n
  }
  __syncthreads();
#pragma unroll
  for (int i = 0; i < 4; ++i) {
    const int lin = t + 256 * i;              // 0..1023
    const int n16 = lin & 15;
    const int kp4l = (lin >> 4) & 7;
    const int nb16l = lin >> 7;               // 0..7
    const unsigned v = *(const unsigned*)(Sb + (nb16l * 16 + n16) * 36 + kp4l * 4);
    const size_t D = ((size_t)(nt * 8 + nb16l) * 512 + kt * 8 + kp4l) * 16 + n16;
    codes[D] = v;
  }
}

// ---- pre-pass 3: scales fp32 [k][nb] -> f16x2 pairs [nb][kp] ----
__global__ __launch_bounds__(256) void prep_scales(const float* __restrict__ scales,
                                                   unsigned* __restrict__ scalesp) {
  const int g = blockIdx.x * 256 + threadIdx.x;
  if (g >= SC_ROW * 2048) return;
  const int kp = g / SC_ROW;
  const int nb = g - kp * SC_ROW;
  const float s0 = scales[(size_t)(2 * kp) * SC_ROW + nb];
  const float s1 = scales[(size_t)(2 * kp + 1) * SC_ROW + nb];
  scalesp[(size_t)nb * 2048 + kp] = hpack(s0, s1);
}

// ---- main: barrier-free fused NF4 GEMM, f16 MFMA ----
// block 128m x 64n, 4 waves (2m x 2n), wave-tile 64m x 32n, grid 704 (16 idle).
// No LDS except 1KB LUT; waves fully autonomous; 2-deep named-reg prefetch.
__global__ __launch_bounds__(256) void nf4_gemm16(
    const unsigned* __restrict__ codes, const unsigned* __restrict__ scalesp,
    const unsigned* __restrict__ wsa, const float* __restrict__ bias,
    float* __restrict__ out) {
  // XCD partition: xcd = bid&7 owns an n-slice across ALL m (codes slice 2.75MB -> L2)
  const int bid = blockIdx.x;
  const int x = bid & 7;
  const int local = bid >> 3;          // 0..87
  const int m_idx = local & 3;
  const int nl = local >> 2;           // 0..21
  const int S = (x < 4) ? x * 22 : 88 + (x - 4) * 21;
  const int cnt = (x < 4) ? 22 : 21;
  if (nl >= cnt) return;               // uniform per block
  const int n_tile = (S + nl) * 64;
  const int m_tile = m_idx * 128;

  __shared__ unsigned LutU[256];       // byte -> f16x2 (even-k val, odd-k val)
  const int t = threadIdx.x;
  LutU[t] = hpack(NF4[(t >> 4) & 15], NF4[t & 15]);
  __syncthreads();

  const int lane = t & 63;
  const int wid = t >> 6;
  const int wm = (wid >> 1) * 64;
  const int wn = (wid & 1) * 32;
  const int l15 = lane & 15;
  const int kslice = lane >> 4;        // 0..3
  const int m16w = (m_tile >> 4) + (wid >> 1) * 4;
  const int nf0 = (n_tile + wn) >> 4;
  const int nb64 = n_tile >> 6;

  // u32 base indices; per k-step s add: codes +64, scales +16, A +256
  const unsigned cb0 = (unsigned)nf0 * 8192 + lane;
  const unsigned cb1 = (unsigned)(nf0 + 1) * 8192 + lane;
  const unsigned sb = (unsigned)nb64 * 2048 + kslice * 4;
  const unsigned ab0 = (unsigned)(m16w + 0) * 32768 + lane * 4;
  const unsigned ab1 = (unsigned)(m16w + 1) * 32768 + lane * 4;
  const unsigned ab2 = (unsigned)(m16w + 2) * 32768 + lane * 4;
  const unsigned ab3 = (unsigned)(m16w + 3) * 32768 + lane * 4;

  f32x4 acc[4][2];
#pragma unroll
  for (int i = 0; i < 4; ++i) {
    acc[i][0] = (f32x4){0.f, 0.f, 0.f, 0.f};
    acc[i][1] = (f32x4){0.f, 0.f, 0.f, 0.f};
  }

  auto LOAD = [&](int s, unsigned& c0, unsigned& c1, u32x4& sv, u32x4& A0,
                  u32x4& A1, u32x4& A2, u32x4& A3) {
    c0 = codes[cb0 + 64u * s];
    c1 = codes[cb1 + 64u * s];
    sv = *(const u32x4*)(scalesp + sb + 16u * s);
    A0 = *(const u32x4*)(wsa + ab0 + 256u * s);
    A1 = *(const u32x4*)(wsa + ab1 + 256u * s);
    A2 = *(const u32x4*)(wsa + ab2 + 256u * s);
    A3 = *(const u32x4*)(wsa + ab3 + 256u * s);
  };
  auto STEP = [&](unsigned c0, unsigned c1, const u32x4& sv, const u32x4& A0,
                  const u32x4& A1, const u32x4& A2, const u32x4& A3) {
    H8 a0, a1, a2, a3;
    a0.v = A0; a1.v = A1; a2.v = A2; a3.v = A3;
#pragma unroll
    for (int fn = 0; fn < 2; ++fn) {
      const unsigned cw = fn ? c1 : c0;
      H8 B;
#pragma unroll
      for (int j = 0; j < 4; ++j) {
        const unsigned byte = (cw >> (8 * j)) & 255u;
        B.v[j] = h2mul(LutU[byte], sv[j]);
      }
      acc[0][fn] = __builtin_amdgcn_mfma_f32_16x16x32_f16(a0.h, B.h, acc[0][fn], 0, 0, 0);
      acc[1][fn] = __builtin_amdgcn_mfma_f32_16x16x32_f16(a1.h, B.h, acc[1][fn], 0, 0, 0);
      acc[2][fn] = __builtin_amdgcn_mfma_f32_16x16x32_f16(a2.h, B.h, acc[2][fn], 0, 0, 0);
      acc[3][fn] = __builtin_amdgcn_mfma_f32_16x16x32_f16(a3.h, B.h, acc[3][fn], 0, 0, 0);
    }
  };

  unsigned Xc0, Xc1, Yc0, Yc1;
  u32x4 Xs, Ys, XA0, XA1, XA2, XA3, YA0, YA1, YA2, YA3;
  LOAD(0, Xc0, Xc1, Xs, XA0, XA1, XA2, XA3);
#pragma unroll 1
  for (int s = 0; s < 128; s += 2) {
    const int s1 = (s + 1 < 128) ? s + 1 : 127;
    const int s2 = (s + 2 < 128) ? s + 2 : 127;
    LOAD(s1, Yc0, Yc1, Ys, YA0, YA1, YA2, YA3);
    STEP(Xc0, Xc1, Xs, XA0, XA1, XA2, XA3);
    LOAD(s2, Xc0, Xc1, Xs, XA0, XA1, XA2, XA3);
    STEP(Yc0, Yc1, Ys, YA0, YA1, YA2, YA3);
  }

  // epilogue: C layout col=l15, row=(lane>>4)*4+r
#pragma unroll
  for (int fn = 0; fn < 2; ++fn) {
    const int gc = n_tile + wn + fn * 16 + l15;
    const float bi = bias[gc];
#pragma unroll
    for (int fm = 0; fm < 4; ++fm) {
#pragma unroll
      for (int r = 0; r < 4; ++r) {
        const int gr = m_tile + wm + fm * 16 + kslice * 4 + r;
        out[(size_t)gr * N_DIM + gc] = acc[fm][fn][r] + bi;
      }
    }
  }
}

// ---- fallback (round-1 kernel, proven 155us): used only if ws too small ----
#define FLDS 72
__global__ __launch_bounds__(256) void nf4_gemm_fused(
    const float* __restrict__ x, const int* __restrict__ packed,
    const float* __restrict__ scales, const float* __restrict__ bias,
    float* __restrict__ out) {
  __shared__ unsigned short Alds[128 * FLDS];
  __shared__ unsigned short Blds[128 * FLDS];
  __shared__ float2 Lut[256];
  const int t = threadIdx.x;
  const int bid = blockIdx.x;
  const int swz = (bid & 7) * 43 + (bid >> 3);
  const int m_tile = (swz / 86) * 128;
  const int n_tile = (swz % 86) * 128;
  Lut[t] = make_float2(NF4[(t >> 4) & 15], NF4[t & 15]);
  const int lane = t & 63;
  const int wid = t >> 6;
  const int wm = (wid >> 1) * 64;
  const int wn = (wid & 1) * 64;
  const int l15 = lane & 15;
  const int l4 = lane >> 4;
  f32x4 acc[4][4];
#pragma unroll
  for (int i = 0; i < 4; ++i)
#pragma unroll
    for (int j = 0; j < 4; ++j) acc[i][j] = (f32x4){0.f, 0.f, 0.f, 0.f};
  const int mlane = t & 15;
  const int n_sub = mlane * 8;
  const int k_sub = 4 * (((t >> 4) + mlane) & 15);
  const int c4 = t & 15;
  const int r0 = t >> 4;
  for (int k0 = 0; k0 < K_DIM; k0 += 64) {
    __syncthreads();
#pragma unroll
    for (int i = 0; i < 8; ++i) {
      const int row = r0 + 16 * i;
      f32x4 xv = *(const f32x4*)(x + (size_t)(m_tile + row) * K_DIM + k0 + c4 * 4);
      uint2 d;
      d.x = f2bf(xv[0]) | (f2bf(xv[1]) << 16);
      d.y = f2bf(xv[2]) | (f2bf(xv[3]) << 16);
      *(uint2*)(&Alds[row * FLDS + c4 * 4]) = d;
    }
    {
      const int* pk = packed + (size_t)(k0 + k_sub) * PK_ROW + ((n_tile + n_sub) >> 1);
      i32x4 w[4];
      float s[4];
#pragma unroll
      for (int kk = 0; kk < 4; ++kk) {
        w[kk] = *(const i32x4*)(pk + (size_t)kk * PK_ROW);
        s[kk] = scales[(size_t)(k0 + k_sub + kk) * SC_ROW + ((n_tile + n_sub) >> 6)];
      }
      float v[4][8];
#pragma unroll
      for (int kk = 0; kk < 4; ++kk)
#pragma unroll
        for (int e = 0; e < 4; ++e) {
          const int b = w[kk][e] & 0xFF;
          const float2 p = Lut[b];
          v[kk][2 * e] = p.x * s[kk];
          v[kk][2 * e + 1] = p.y * s[kk];
        }
#pragma unroll
      for (int j = 0; j < 8; ++j) {
        uint2 d;
        d.x = f2bf(v[0][j]) | (f2bf(v[1][j]) << 16);
        d.y = f2bf(v[2][j]) | (f2bf(v[3][j]) << 16);
        *(uint2*)(&Blds[(n_sub + j) * FLDS + k_sub]) = d;
      }
    }
    __syncthreads();
#pragma unroll
    for (int ks = 0; ks < 2; ++ks) {
      bf16x8 af[4], bfv[4];
#pragma unroll
      for (int fm = 0; fm < 4; ++fm)
        af[fm] = *(const bf16x8*)(&Alds[(wm + fm * 16 + l15) * FLDS + ks * 32 + l4 * 8]);
#pragma unroll
      for (int fn = 0; fn < 4; ++fn)
        bfv[fn] = *(const bf16x8*)(&Blds[(wn + fn * 16 + l15) * FLDS + ks * 32 + l4 * 8]);
#pragma unroll
      for (int fm = 0; fm < 4; ++fm)
#pragma unroll
        for (int fn = 0; fn < 4; ++fn)
          acc[fm][fn] = __builtin_amdgcn_mfma_f32_16x16x32_bf16(af[fm], bfv[fn], acc[fm][fn], 0, 0, 0);
    }
  }
#pragma unroll
  for (int fn = 0; fn < 4; ++fn) {
    const float bi = bias[n_tile + wn + fn * 16 + l15];
#pragma unroll
    for (int fm = 0; fm < 4; ++fm)
#pragma unroll
      for (int r = 0; r < 4; ++r) {
        const int gr = m_tile + wm + fm * 16 + l4 * 4 + r;
        out[(size_t)gr * N_DIM + n_tile + wn + fn * 16 + l15] = acc[fm][fn][r] + bi;
      }
  }
}

extern "C" void kernel_launch(void* const* d_in, const int* in_sizes, int n_in,
                              void* d_out, int out_size, void* d_ws, size_t ws_size,
                              hipStream_t stream) {
  const float* x = (const float*)d_in[0];
  const int* packed = (const int*)d_in[1];
  const float* scales = (const float*)d_in[2];
  const float* bias = (const float*)d_in[3];
  float* out = (float*)d_out;

  const size_t A_BYTES = (size_t)M_DIM * K_DIM * 2;            // 4,194,304
  const size_t C_BYTES = (size_t)688 * 512 * 16 * 4;           // 22,544,384
  const size_t S_BYTES = (size_t)SC_ROW * 2048 * 4;            // 1,409,024
  const size_t need = A_BYTES + C_BYTES + S_BYTES;

  if (ws_size >= need) {
    unsigned* wsa = (unsigned*)d_ws;
    unsigned* codes = (unsigned*)((char*)d_ws + A_BYTES);
    unsigned* scalesp = (unsigned*)((char*)d_ws + A_BYTES + C_BYTES);
    conv_a16<<<dim3(1024), dim3(256), 0, stream>>>(x, wsa);
    prep_codes<<<dim3(5504), dim3(256), 0, stream>>>(packed, codes);
    prep_scales<<<dim3(1376), dim3(256), 0, stream>>>(scales, scalesp);
    nf4_gemm16<<<dim3(704), dim3(256), 0, stream>>>(codes, scalesp, wsa, bias, out);
  } else {
    nf4_gemm_fused<<<dim3(344), dim3(256), 0, stream>>>(x, packed, scales, bias, out);
  }
}